// Round 2
// baseline (878.700 us; speedup 1.0000x reference)
//
#include <hip/hip_runtime.h>

// Problem constants (fixed by the reference):
//   expert_outputs: [E=8, C=8192, D=1024] f32
//   weights:        [E, C] f32
//   token_indices:  [E, C] (harness delivers integer inputs as int32!)
//   out:            [B=8, S=4096, D=1024] f32  (flat: 32768 x 1024)
#define E_EXP 8
#define C_CAP 8192
#define D_DIM 1024
#define N_ROWS (E_EXP * C_CAP)      // 65536
#define N_TOK  (8 * 4096)           // 32768

// One block per (e,c) row. 256 threads x float4 = 1024 elements = one row.
// Scatter-add with device-scope atomics (token collisions are expected:
// avg 2 rows/token with random indices).
__global__ __launch_bounds__(256) void expert_combine_scatter(
    const float* __restrict__ expert_outputs,
    const float* __restrict__ weights,
    const int* __restrict__ token_indices,   // int32 per harness contract
    float* __restrict__ out)
{
    const int row = blockIdx.x;                       // 0 .. N_ROWS-1
    const int tok = token_indices[row];               // uniform per block
    const float w = weights[row];                     // uniform per block

    const float4* __restrict__ src =
        reinterpret_cast<const float4*>(expert_outputs + (size_t)row * D_DIM);
    float* __restrict__ dst = out + (size_t)tok * D_DIM;

    const int t = threadIdx.x;                        // 0 .. 255
    float4 v = src[t];                                // coalesced 16B/lane

    const int base = t * 4;
    atomicAdd(dst + base + 0, v.x * w);
    atomicAdd(dst + base + 1, v.y * w);
    atomicAdd(dst + base + 2, v.z * w);
    atomicAdd(dst + base + 3, v.w * w);
}

extern "C" void kernel_launch(void* const* d_in, const int* in_sizes, int n_in,
                              void* d_out, int out_size, void* d_ws, size_t ws_size,
                              hipStream_t stream) {
    const float* expert_outputs = (const float*)d_in[0];
    const float* weights        = (const float*)d_in[1];
    const int*   token_indices  = (const int*)d_in[2];
    float* out = (float*)d_out;

    // Output buffer is poisoned (0xAA) before timing and NOT re-zeroed
    // between replays — zero it ourselves every call (deterministic).
    hipMemsetAsync(out, 0, (size_t)out_size * sizeof(float), stream);

    expert_combine_scatter<<<N_ROWS, 256, 0, stream>>>(
        expert_outputs, weights, token_indices, out);
}

// Round 3
// 99.939 us; speedup vs baseline: 8.7924x; 8.7924x over previous
//
#include <hip/hip_runtime.h>

// Problem constants (fixed by the reference):
//   expert_outputs: [E=8, C=8192, D=1024] f32
//   weights:        [E, C] f32
//   token_indices:  [E, C] int32 (harness converts integer inputs to int32)
//   out:            [B=8, S=4096, D=1024] f32  (flat: 32768 x 1024)
#define E_EXP 8
#define C_CAP 8192
#define D_DIM 1024
#define N_ROWS (E_EXP * C_CAP)      // 65536  (row ids fit in ushort!)
#define N_TOK  (8 * 4096)           // 32768
#define SLOTS_K 16                  // fixed slots per token (Poisson(2) tail ~1e-12)
#define OVF_MAX 4096                // overflow list capacity (never hit in practice)

// ---------------- Pass 1: build inverse index (token -> row list) ----------
__global__ __launch_bounds__(256) void combine_build(
    const int* __restrict__ token_indices,
    int* __restrict__ count,            // [N_TOK], pre-zeroed
    unsigned short* __restrict__ slots, // [N_TOK * SLOTS_K]
    int* __restrict__ ovf_cnt,          // [1], pre-zeroed
    int* __restrict__ ovf_list)         // [OVF_MAX]
{
    const int row = blockIdx.x * 256 + threadIdx.x;   // 0 .. N_ROWS-1
    const int tok = token_indices[row];
    const int slot = atomicAdd(&count[tok], 1);
    if (slot < SLOTS_K) {
        slots[(size_t)tok * SLOTS_K + slot] = (unsigned short)row;
    } else {
        const int p = atomicAdd(ovf_cnt, 1);
        if (p < OVF_MAX) ovf_list[p] = row;
    }
}

// ---------------- Pass 2: gather per token (no output atomics) -------------
__global__ __launch_bounds__(256) void combine_gather(
    const float* __restrict__ expert_outputs,
    const float* __restrict__ weights,
    const int* __restrict__ count,
    const unsigned short* __restrict__ slots,
    float* __restrict__ out)
{
    const int tok = blockIdx.x;                       // 0 .. N_TOK-1
    const int n = min(count[tok], SLOTS_K);
    const int t = threadIdx.x;                        // 0 .. 255

    float4 acc = make_float4(0.f, 0.f, 0.f, 0.f);
    for (int r = 0; r < n; ++r) {
        const int row = slots[(size_t)tok * SLOTS_K + r];   // block-uniform
        const float w = weights[row];                        // block-uniform
        const float4 v = reinterpret_cast<const float4*>(
            expert_outputs + (size_t)row * D_DIM)[t];        // coalesced 16B/lane
        acc.x += w * v.x;
        acc.y += w * v.y;
        acc.z += w * v.z;
        acc.w += w * v.w;
    }
    // Plain store — also writes zeros for tokens with no contributions,
    // which doubles as the output initialization (poison-safe).
    reinterpret_cast<float4*>(out + (size_t)tok * D_DIM)[t] = acc;
}

// ---------------- Pass 3: overflow cleanup (empty in practice) -------------
__global__ __launch_bounds__(256) void combine_overflow(
    const float* __restrict__ expert_outputs,
    const float* __restrict__ weights,
    const int* __restrict__ token_indices,
    const int* __restrict__ ovf_cnt,
    const int* __restrict__ ovf_list,
    float* __restrict__ out)
{
    const int n = min(*ovf_cnt, OVF_MAX);
    for (int i = blockIdx.x; i < n; i += gridDim.x) {
        const int row = ovf_list[i];
        const int tok = token_indices[row];
        const float w = weights[row];
        const float4 v = reinterpret_cast<const float4*>(
            expert_outputs + (size_t)row * D_DIM)[threadIdx.x];
        float* dst = out + (size_t)tok * D_DIM + threadIdx.x * 4;
        atomicAdd(dst + 0, w * v.x);
        atomicAdd(dst + 1, w * v.y);
        atomicAdd(dst + 2, w * v.z);
        atomicAdd(dst + 3, w * v.w);
    }
}

extern "C" void kernel_launch(void* const* d_in, const int* in_sizes, int n_in,
                              void* d_out, int out_size, void* d_ws, size_t ws_size,
                              hipStream_t stream) {
    const float* expert_outputs = (const float*)d_in[0];
    const float* weights        = (const float*)d_in[1];
    const int*   token_indices  = (const int*)d_in[2];
    float* out = (float*)d_out;

    // Workspace layout (all within d_ws):
    //   count    : N_TOK int            (128 KB)
    //   ovf_cnt  : 1 int
    //   ovf_list : OVF_MAX int          (16 KB)
    //   slots    : N_TOK*SLOTS_K ushort (1 MB)
    int* count   = (int*)d_ws;
    int* ovf_cnt = count + N_TOK;
    int* ovf_list = ovf_cnt + 1;
    unsigned short* slots = (unsigned short*)(ovf_list + OVF_MAX);

    // Zero the counters every call (deterministic across graph replays).
    hipMemsetAsync(count, 0, (size_t)(N_TOK + 1 + OVF_MAX) * sizeof(int), stream);

    combine_build<<<N_ROWS / 256, 256, 0, stream>>>(
        token_indices, count, slots, ovf_cnt, ovf_list);

    combine_gather<<<N_TOK, 256, 0, stream>>>(
        expert_outputs, weights, count, slots, out);

    combine_overflow<<<8, 256, 0, stream>>>(
        expert_outputs, weights, token_indices, ovf_cnt, ovf_list, out);
}

// Round 4
// 93.526 us; speedup vs baseline: 9.3952x; 1.0686x over previous
//
#include <hip/hip_runtime.h>

// Problem constants (fixed by the reference):
//   expert_outputs: [E=8, C=8192, D=1024] f32
//   weights:        [E, C] f32
//   token_indices:  [E, C] int32 (harness converts integer inputs to int32)
//   out:            [B=8, S=4096, D=1024] f32  (flat: 32768 x 1024)
#define E_EXP 8
#define C_CAP 8192
#define D_DIM 1024
#define N_ROWS (E_EXP * C_CAP)      // 65536  (row ids fit in ushort)
#define N_TOK  (8 * 4096)           // 32768
#define SLOTS_K 16                  // slots per token (Poisson(2): P(>16) ~ 1e-12)

typedef float f32x4 __attribute__((ext_vector_type(4)));

// ---------------- Pass 1: build inverse index (token -> row list) ----------
__global__ __launch_bounds__(256) void combine_build(
    const int* __restrict__ token_indices,
    int* __restrict__ count,            // [N_TOK], pre-zeroed
    unsigned short* __restrict__ slots) // [N_TOK * SLOTS_K]
{
    const int row = blockIdx.x * 256 + threadIdx.x;   // 0 .. N_ROWS-1
    const int tok = token_indices[row];
    const int slot = atomicAdd(&count[tok], 1);
    if (slot < SLOTS_K) {
        slots[(size_t)tok * SLOTS_K + slot] = (unsigned short)row;
    }
    // If a token ever exceeds SLOTS_K rows, gather takes the exact
    // rare-path scan below — no overflow list needed.
}

// ---------------- Pass 2: gather per token (no output atomics) -------------
__global__ __launch_bounds__(256) void combine_gather(
    const float* __restrict__ expert_outputs,
    const float* __restrict__ weights,
    const int* __restrict__ token_indices,
    const int* __restrict__ count,
    const unsigned short* __restrict__ slots,
    float* __restrict__ out)
{
    const int tok = blockIdx.x;                       // 0 .. N_TOK-1
    const int t = threadIdx.x;                        // 0 .. 255
    const int n = count[tok];

    f32x4 acc = (f32x4)(0.f);

    if (__builtin_expect(n <= SLOTS_K, 1)) {
        // Load all 16 slot ids in one 32B transaction (block-uniform).
        union { uint4 u[2]; unsigned short id[SLOTS_K]; } s;
        const uint4* sp = reinterpret_cast<const uint4*>(
            slots + (size_t)tok * SLOTS_K);
        s.u[0] = sp[0];
        s.u[1] = sp[1];

        #pragma unroll 2
        for (int r = 0; r < n; ++r) {
            const int row = s.id[r];                          // block-uniform
            const float w = weights[row];                     // block-uniform
            const f32x4 v = __builtin_nontemporal_load(
                reinterpret_cast<const f32x4*>(
                    expert_outputs + (size_t)row * D_DIM) + t);
            acc += w * v;
        }
    } else {
        // Exact rare path (never taken for this input distribution):
        // scan every row for matches.
        for (int row = 0; row < N_ROWS; ++row) {
            if (token_indices[row] == tok) {
                const float w = weights[row];
                const f32x4 v = __builtin_nontemporal_load(
                    reinterpret_cast<const f32x4*>(
                        expert_outputs + (size_t)row * D_DIM) + t);
                acc += w * v;
            }
        }
    }

    // Plain (nontemporal) store — zero rows included, so this doubles as
    // output initialization (poison-safe, no memset of d_out needed).
    __builtin_nontemporal_store(acc,
        reinterpret_cast<f32x4*>(out + (size_t)tok * D_DIM) + t);
}

extern "C" void kernel_launch(void* const* d_in, const int* in_sizes, int n_in,
                              void* d_out, int out_size, void* d_ws, size_t ws_size,
                              hipStream_t stream) {
    const float* expert_outputs = (const float*)d_in[0];
    const float* weights        = (const float*)d_in[1];
    const int*   token_indices  = (const int*)d_in[2];
    float* out = (float*)d_out;

    // Workspace layout:
    //   count : N_TOK int            (128 KB)
    //   slots : N_TOK*SLOTS_K ushort (1 MB)
    int* count = (int*)d_ws;
    unsigned short* slots = (unsigned short*)(count + N_TOK);

    // Zero the counters every call (deterministic across graph replays).
    hipMemsetAsync(count, 0, (size_t)N_TOK * sizeof(int), stream);

    combine_build<<<N_ROWS / 256, 256, 0, stream>>>(
        token_indices, count, slots);

    combine_gather<<<N_TOK, 256, 0, stream>>>(
        expert_outputs, weights, token_indices, count, slots, out);
}